// Round 1
// baseline (23939.769 us; speedup 1.0000x reference)
//
#include <hip/hip_runtime.h>
#include <stdint.h>

// ---------------- problem constants ----------------
#define T_STEPS 1000
#define B_SZ    32
#define NI      512
#define NH      1024
#define NO      256

#define NBLK    256   // scan blocks; each owns SLICE=4 postsyn neurons x all 32 batches
#define SLICE   4

// ---------------- ws layout (bytes) ----------------
#define OFF_IEXT 0ull
#define SZ_IEXT  ((unsigned long long)T_STEPS * B_SZ * NH * 4ull)   // 131,072,000
#define OFF_WP   (OFF_IEXT + SZ_IEXT)
#define SZ_WP    ((unsigned long long)NH * NH * 4ull)               // 4 MiB
#define OFF_RATE (OFF_WP + SZ_WP)
#define SZ_RATE  ((unsigned long long)B_SZ * NH * 4ull)             // 128 KiB
#define OFF_SYNC (OFF_RATE + SZ_RATE)
#define SZ_SYNC  16384ull

// ---------------- agent-scope helpers ----------------
__device__ __forceinline__ unsigned ld_agent(const unsigned* p) {
  return __hip_atomic_load(p, __ATOMIC_RELAXED, __HIP_MEMORY_SCOPE_AGENT);
}
__device__ __forceinline__ void st_agent(unsigned* p, unsigned v) {
  __hip_atomic_store(p, v, __ATOMIC_RELAXED, __HIP_MEMORY_SCOPE_AGENT);
}

// generation barrier: gen is monotone (= number of completed steps). No
// load-vs-RMW ordering race: spin condition uses the loop's own t+1.
__device__ __forceinline__ void grid_barrier(unsigned* cnt, unsigned* gen, unsigned tplus1) {
  __syncthreads();
  if (threadIdx.x == 0) {
    unsigned a = __hip_atomic_fetch_add(cnt, 1u, __ATOMIC_ACQ_REL, __HIP_MEMORY_SCOPE_AGENT);
    if (a == NBLK - 1) {
      __hip_atomic_store(cnt, 0u, __ATOMIC_RELAXED, __HIP_MEMORY_SCOPE_AGENT);
      __hip_atomic_store(gen, tplus1, __ATOMIC_RELEASE, __HIP_MEMORY_SCOPE_AGENT);
    } else {
      while (__hip_atomic_load(gen, __ATOMIC_RELAXED, __HIP_MEMORY_SCOPE_AGENT) < tplus1)
        __builtin_amdgcn_s_sleep(1);
      (void)__hip_atomic_load(gen, __ATOMIC_ACQUIRE, __HIP_MEMORY_SCOPE_AGENT);
    }
  }
  __syncthreads();
}

// ---------------- kernel 1: pack W_rec into per-block slices ----------------
// WP[(p*1024 + i)*4 + jj] = W_rec[(4p+jj)*1024 + i]  -> 16 KB contiguous per block (L1-resident)
__global__ __launch_bounds__(256) void prep_wp(const float* __restrict__ Wrec,
                                               float* __restrict__ WP) {
  const int p = blockIdx.x;
  const int t = threadIdx.x;
#pragma unroll
  for (int it = 0; it < 4; ++it) {
    const int i = it * 256 + t;
    float4 w;
    w.x = Wrec[(size_t)(SLICE * p + 0) * NH + i];
    w.y = Wrec[(size_t)(SLICE * p + 1) * NH + i];
    w.z = Wrec[(size_t)(SLICE * p + 2) * NH + i];
    w.w = Wrec[(size_t)(SLICE * p + 3) * NH + i];
    ((float4*)WP)[(size_t)p * NH + i] = w;
  }
}

// ---------------- kernel 2: I_ext = x @ W_in^T  (fp32 tiled) ----------------
#define GBM 128
#define GBN 128
#define GBK 16
__global__ __launch_bounds__(256) void gemm_in(const float* __restrict__ X,
                                               const float* __restrict__ Win,
                                               float* __restrict__ I) {
  __shared__ float As[GBK][GBM + 4];
  __shared__ float Bs[GBK][GBN + 4];
  const int tid = threadIdx.x;
  const int m0 = blockIdx.x * GBM;
  const int n0 = blockIdx.y * GBN;
  const int tm = tid >> 4, tn = tid & 15;
  const int lr = tid >> 1, lk = (tid & 1) * 8;
  float acc[8][8] = {};
  for (int k0 = 0; k0 < NI; k0 += GBK) {
    float4 a0 = *(const float4*)&X[(size_t)(m0 + lr) * NI + k0 + lk];
    float4 a1 = *(const float4*)&X[(size_t)(m0 + lr) * NI + k0 + lk + 4];
    float4 b0 = *(const float4*)&Win[(size_t)(n0 + lr) * NI + k0 + lk];
    float4 b1 = *(const float4*)&Win[(size_t)(n0 + lr) * NI + k0 + lk + 4];
    As[lk + 0][lr] = a0.x; As[lk + 1][lr] = a0.y; As[lk + 2][lr] = a0.z; As[lk + 3][lr] = a0.w;
    As[lk + 4][lr] = a1.x; As[lk + 5][lr] = a1.y; As[lk + 6][lr] = a1.z; As[lk + 7][lr] = a1.w;
    Bs[lk + 0][lr] = b0.x; Bs[lk + 1][lr] = b0.y; Bs[lk + 2][lr] = b0.z; Bs[lk + 3][lr] = b0.w;
    Bs[lk + 4][lr] = b1.x; Bs[lk + 5][lr] = b1.y; Bs[lk + 6][lr] = b1.z; Bs[lk + 7][lr] = b1.w;
    __syncthreads();
#pragma unroll
    for (int k = 0; k < GBK; ++k) {
      float av[8], bv[8];
      *(float4*)&av[0] = *(const float4*)&As[k][tm * 8];
      *(float4*)&av[4] = *(const float4*)&As[k][tm * 8 + 4];
      *(float4*)&bv[0] = *(const float4*)&Bs[k][tn * 8];
      *(float4*)&bv[4] = *(const float4*)&Bs[k][tn * 8 + 4];
#pragma unroll
      for (int i2 = 0; i2 < 8; ++i2)
#pragma unroll
        for (int j2 = 0; j2 < 8; ++j2) acc[i2][j2] += av[i2] * bv[j2];
    }
    __syncthreads();
  }
#pragma unroll
  for (int i2 = 0; i2 < 8; ++i2) {
    float4 c0 = {acc[i2][0], acc[i2][1], acc[i2][2], acc[i2][3]};
    float4 c1 = {acc[i2][4], acc[i2][5], acc[i2][6], acc[i2][7]};
    *(float4*)&I[(size_t)(m0 + tm * 8 + i2) * NH + n0 + tn * 8] = c0;
    *(float4*)&I[(size_t)(m0 + tm * 8 + i2) * NH + n0 + tn * 8 + 4] = c1;
  }
}

// ---------------- kernel 3: persistent 1000-step scan ----------------
// 256 blocks x 256 threads. Block p owns j in [4p,4p+4), all 32 batches.
// Threads 0..127 hold state for pair q=(b,jj); threads 128..255 help gather.
__global__ __launch_bounds__(256) void scan_rsnn(const float* __restrict__ Iext,
                                                 const float* __restrict__ WP,
                                                 float* __restrict__ rate,
                                                 unsigned* sbuf, unsigned* cnt,
                                                 unsigned* gen) {
  __shared__ unsigned bm[32][32];   // [batch][word] bit x of word w <-> presyn j = 32w+x
  __shared__ unsigned nib[32];      // per-batch 4-bit spike nibble of this block
  __shared__ float psum[256];

  const int p   = blockIdx.x;
  const int tid = threadIdx.x;
  const int q   = tid & 127;
  const int half = tid >> 7;
  const int b   = q >> 2;
  const int jj  = q & 3;
  const float* wbase = WP + (size_t)p * (NH * SLICE) + jj;

  float v = -60.0f, a1 = 0.0f, a2 = 0.0f, refr = 0.0f, h = 0.0f, psc = 0.0f;
  int scount = 0;
  const float D1 = 0.90483741803595957f;   // exp(-0.1)
  const float D2 = 0.81873075307798186f;   // exp(-0.2) == decay_syn

  float ipre = (tid < 128) ? Iext[(size_t)b * NH + SLICE * p + jj] : 0.0f;

  for (int t = 0; t < T_STEPS; ++t) {
    const int par = t & 1;
    bool spike = false;
    if (tid < 128) {
      const float I = ipre + psc;
      a1 *= D1;
      a2 *= D2;
      v = v + ((-60.0f - v) / 20.0f + (I + a1 + a2) / 2.0f);
      const bool inref = refr > 0.0f;
      if (inref) v = -60.0f;
      spike = (!inref) && (v >= -45.0f);
      if (spike) {
        v = -60.0f; a1 += 1.0f; a2 += -2.0f; refr = 2.0f; scount++;
      } else {
        refr = fmaxf(refr - 1.0f, 0.0f);
      }
    }
    // pack this block's spikes: ballot -> per-batch nibble -> 4 exclusive words
    unsigned long long bal = __ballot(spike ? 1 : 0);
    if (tid < 128 && (tid & 3) == 0) nib[b] = (unsigned)((bal >> (tid & 63)) & 0xFull);
    // zero bm while waiting on nib
    {
      unsigned* bmf = &bm[0][0];
      bmf[tid] = 0u; bmf[tid + 256] = 0u; bmf[tid + 512] = 0u; bmf[tid + 768] = 0u;
    }
    __syncthreads();
    if (tid < 4) {
      unsigned u = 0;
#pragma unroll
      for (int k2 = 0; k2 < 8; ++k2) u |= nib[tid * 8 + k2] << (4 * k2);
      st_agent(&sbuf[(size_t)(par * NBLK + p) * 4 + tid], u);
    }
    // prefetch next step's external current (hides LLC/HBM latency)
    const int tn2 = (t + 1 < T_STEPS) ? t + 1 : t;
    float inext = (tid < 128) ? Iext[(size_t)(tn2 * B_SZ + b) * NH + SLICE * p + jj] : 0.0f;

    grid_barrier(cnt, gen, (unsigned)(t + 1));

    // read all 256 producers' words (thread tid reads producer tid), transpose to bm
    {
      const unsigned* src = &sbuf[(size_t)(par * NBLK + tid) * 4];
      unsigned ww0 = ld_agent(src + 0), ww1 = ld_agent(src + 1);
      unsigned ww2 = ld_agent(src + 2), ww3 = ld_agent(src + 3);
      const int wi = tid >> 3;          // word index for presyn j = 4*tid..4*tid+3
      const int sh = 4 * (tid & 7);
      unsigned ww[4] = {ww0, ww1, ww2, ww3};
#pragma unroll
      for (int g = 0; g < 4; ++g) {     // batch group 8g..8g+7
        unsigned u = ww[g];
        if (u) {
#pragma unroll
          for (int k2 = 0; k2 < 8; ++k2) {
            unsigned nb = (u >> (4 * k2)) & 0xFu;
            if (nb) atomicOr(&bm[8 * g + k2][wi], nb << sh);
          }
        }
      }
    }
    __syncthreads();

    // sparse gather: rec[b,j] = sum over spiking presyn i of W_rec[j,i]
    float s = 0.0f;
    for (int w = half * 16; w < half * 16 + 16; ++w) {
      unsigned m = bm[b][w];
      while (m) {
        const int bit = __builtin_ctz(m);
        m &= m - 1;
        s += wbase[(size_t)(w * 32 + bit) * SLICE];
      }
    }
    psum[tid] = s;
    __syncthreads();
    if (tid < 128) {
      const float rec = s + psum[tid + 128];
      h = D2 * h + rec;
      psc = D2 * psc + h;   // psc uses updated h (matches reference)
    }
    ipre = inext;
  }

  if (tid < 128) rate[(size_t)b * NH + SLICE * p + jj] = (float)scount / 1000.0f;
}

// ---------------- kernel 4: out = rate @ W_out^T ----------------
__global__ __launch_bounds__(256) void out_gemv(const float* __restrict__ rate,
                                                const float* __restrict__ Wout,
                                                float* __restrict__ out) {
  __shared__ float rs[NH];
  const int b = blockIdx.x, tid = threadIdx.x;
  for (int i = tid; i < NH; i += 256) rs[i] = rate[(size_t)b * NH + i];
  __syncthreads();
  const float* wr = Wout + (size_t)tid * NH;
  float s = 0.0f;
  for (int hh = 0; hh < NH; hh += 4) {
    float4 w4 = *(const float4*)&wr[hh];
    s += rs[hh] * w4.x + rs[hh + 1] * w4.y + rs[hh + 2] * w4.z + rs[hh + 3] * w4.w;
  }
  out[(size_t)b * NO + tid] = s;
}

// ---------------- launch ----------------
extern "C" void kernel_launch(void* const* d_in, const int* in_sizes, int n_in,
                              void* d_out, int out_size, void* d_ws, size_t ws_size,
                              hipStream_t stream) {
  const float* x    = (const float*)d_in[0];
  const float* Win  = (const float*)d_in[1];
  const float* Wrec = (const float*)d_in[2];
  const float* Wout = (const float*)d_in[3];
  float* out = (float*)d_out;

  char* ws = (char*)d_ws;
  float* Iext = (float*)(ws + OFF_IEXT);
  float* WP   = (float*)(ws + OFF_WP);
  float* rate = (float*)(ws + OFF_RATE);
  unsigned* sync = (unsigned*)(ws + OFF_SYNC);
  unsigned* cnt  = sync;          // +0
  unsigned* gen  = sync + 1;      // +4
  unsigned* sbuf = sync + 8;      // +32B, 2*256*4 words = 8 KiB

  hipMemsetAsync(sync, 0, SZ_SYNC, stream);
  prep_wp<<<dim3(NBLK), dim3(256), 0, stream>>>(Wrec, WP);
  gemm_in<<<dim3((T_STEPS * B_SZ) / GBM, NH / GBN), dim3(256), 0, stream>>>(x, Win, Iext);
  scan_rsnn<<<dim3(NBLK), dim3(256), 0, stream>>>(Iext, WP, rate, sbuf, cnt, gen);
  out_gemv<<<dim3(B_SZ), dim3(256), 0, stream>>>(rate, Wout, out);
}

// Round 2
// 11813.945 us; speedup vs baseline: 2.0264x; 2.0264x over previous
//
#include <hip/hip_runtime.h>
#include <stdint.h>

// ---------------- problem constants ----------------
#define T_STEPS 1000
#define B_SZ    32
#define NI      512
#define NH      1024
#define NO      256

#define NBLK    256   // scan blocks; block p owns SLICE=4 postsyn neurons x all 32 batches
#define SLICE   4

typedef unsigned long long u64;

// ---------------- ws layout (bytes) ----------------
#define OFF_IEXT 0ull
#define SZ_IEXT  ((unsigned long long)T_STEPS * B_SZ * NH * 4ull)   // 131,072,000
#define OFF_WP   (OFF_IEXT + SZ_IEXT)
#define SZ_WP    ((unsigned long long)NH * NH * 4ull)               // 4 MiB
#define OFF_RATE (OFF_WP + SZ_WP)
#define SZ_RATE  ((unsigned long long)B_SZ * NH * 4ull)             // 128 KiB
#define OFF_SYNC (OFF_RATE + SZ_RATE)
#define SZ_SYNC  16384ull                                           // 2 par x 256 prod x 4 u64

// ---------------- agent-scope helpers ----------------
// Relaxed agent-scope atomics bypass the non-coherent per-XCD caches (verified
// R1: spike exchange via these passed absmax over 1000 steps).
__device__ __forceinline__ u64 ld64_agent(const u64* p) {
  return __hip_atomic_load(p, __ATOMIC_RELAXED, __HIP_MEMORY_SCOPE_AGENT);
}
__device__ __forceinline__ void st64_agent(u64* p, u64 v) {
  __hip_atomic_store(p, v, __ATOMIC_RELAXED, __HIP_MEMORY_SCOPE_AGENT);
}

// ---------------- kernel 1: pack W_rec into per-block slices ----------------
// WP[(p*1024 + i)*4 + jj] = W_rec[(4p+jj)*1024 + i]  -> 16 KB contiguous per block
__global__ __launch_bounds__(256) void prep_wp(const float* __restrict__ Wrec,
                                               float* __restrict__ WP) {
  const int p = blockIdx.x;
  const int t = threadIdx.x;
#pragma unroll
  for (int it = 0; it < 4; ++it) {
    const int i = it * 256 + t;
    float4 w;
    w.x = Wrec[(size_t)(SLICE * p + 0) * NH + i];
    w.y = Wrec[(size_t)(SLICE * p + 1) * NH + i];
    w.z = Wrec[(size_t)(SLICE * p + 2) * NH + i];
    w.w = Wrec[(size_t)(SLICE * p + 3) * NH + i];
    ((float4*)WP)[(size_t)p * NH + i] = w;
  }
}

// ---------------- kernel 2: I_ext = x @ W_in^T  (fp32 tiled) ----------------
#define GBM 128
#define GBN 128
#define GBK 16
__global__ __launch_bounds__(256) void gemm_in(const float* __restrict__ X,
                                               const float* __restrict__ Win,
                                               float* __restrict__ I) {
  __shared__ float As[GBK][GBM + 4];
  __shared__ float Bs[GBK][GBN + 4];
  const int tid = threadIdx.x;
  const int m0 = blockIdx.x * GBM;
  const int n0 = blockIdx.y * GBN;
  const int tm = tid >> 4, tn = tid & 15;
  const int lr = tid >> 1, lk = (tid & 1) * 8;
  float acc[8][8] = {};
  for (int k0 = 0; k0 < NI; k0 += GBK) {
    float4 a0 = *(const float4*)&X[(size_t)(m0 + lr) * NI + k0 + lk];
    float4 a1 = *(const float4*)&X[(size_t)(m0 + lr) * NI + k0 + lk + 4];
    float4 b0 = *(const float4*)&Win[(size_t)(n0 + lr) * NI + k0 + lk];
    float4 b1 = *(const float4*)&Win[(size_t)(n0 + lr) * NI + k0 + lk + 4];
    As[lk + 0][lr] = a0.x; As[lk + 1][lr] = a0.y; As[lk + 2][lr] = a0.z; As[lk + 3][lr] = a0.w;
    As[lk + 4][lr] = a1.x; As[lk + 5][lr] = a1.y; As[lk + 6][lr] = a1.z; As[lk + 7][lr] = a1.w;
    Bs[lk + 0][lr] = b0.x; Bs[lk + 1][lr] = b0.y; Bs[lk + 2][lr] = b0.z; Bs[lk + 3][lr] = b0.w;
    Bs[lk + 4][lr] = b1.x; Bs[lk + 5][lr] = b1.y; Bs[lk + 6][lr] = b1.z; Bs[lk + 7][lr] = b1.w;
    __syncthreads();
#pragma unroll
    for (int k = 0; k < GBK; ++k) {
      float av[8], bv[8];
      *(float4*)&av[0] = *(const float4*)&As[k][tm * 8];
      *(float4*)&av[4] = *(const float4*)&As[k][tm * 8 + 4];
      *(float4*)&bv[0] = *(const float4*)&Bs[k][tn * 8];
      *(float4*)&bv[4] = *(const float4*)&Bs[k][tn * 8 + 4];
#pragma unroll
      for (int i2 = 0; i2 < 8; ++i2)
#pragma unroll
        for (int j2 = 0; j2 < 8; ++j2) acc[i2][j2] += av[i2] * bv[j2];
    }
    __syncthreads();
  }
#pragma unroll
  for (int i2 = 0; i2 < 8; ++i2) {
    float4 c0 = {acc[i2][0], acc[i2][1], acc[i2][2], acc[i2][3]};
    float4 c1 = {acc[i2][4], acc[i2][5], acc[i2][6], acc[i2][7]};
    *(float4*)&I[(size_t)(m0 + tm * 8 + i2) * NH + n0 + tn * 8] = c0;
    *(float4*)&I[(size_t)(m0 + tm * 8 + i2) * NH + n0 + tn * 8 + 4] = c1;
  }
}

// ---------------- kernel 3: persistent 1000-step scan ----------------
// Sync: self-tagged 64-bit publications, point-to-point polling. No counter
// barrier. Producer p, step t writes 4 u64s: lo32 = 32 spike bits (8 batches x
// 4 neuron nibbles), hi32 = t+1. Consumer thread tid polls producer tid's 4
// u64s until all tags == t+1. Parity double-buffer; overwrite-safe because
// block A publishes (t+2) only after consuming all (t+1), which implies every
// block B published (t+1), which implies B consumed A's (t).
__global__ __launch_bounds__(256) void scan_rsnn(const float* __restrict__ Iext,
                                                 const float* __restrict__ WP,
                                                 float* __restrict__ rate,
                                                 u64* sbuf) {
  __shared__ unsigned raw[4][NBLK];   // [batch-group g][producer p], bank = p%32: conflict-free
  __shared__ unsigned bm[32][32];     // [word w][batch b], bank = b: gather is broadcast, free
  __shared__ float psum[256];

  const int p    = blockIdx.x;
  const int tid  = threadIdx.x;
  const int q    = tid & 127;
  const int half = tid >> 7;
  const int b    = q >> 2;
  const int jj   = q & 3;
  const float* wbase = WP + (size_t)p * (NH * SLICE) + jj;

  // bm-build assignment: thread builds words {cw0, cw0+8, cw0+16, cw0+24} of batch cb
  const int cb   = tid & 31;
  const int cw0  = tid >> 5;      // 0..7
  const int csh  = 4 * (cb & 7);
  const int crow = cb >> 3;

  // publisher role: tid 0,1 hold wave0's ballot (batches 0..15), tid 64,65 wave1's
  int widx = -1;
  if (tid == 0) widx = 0; else if (tid == 1) widx = 1;
  else if (tid == 64) widx = 2; else if (tid == 65) widx = 3;

  float v = -60.0f, a1 = 0.0f, a2 = 0.0f, refr = 0.0f, h = 0.0f, psc = 0.0f;
  int scount = 0;
  const float D1 = 0.90483741803595957f;   // exp(-0.1)
  const float D2 = 0.81873075307798186f;   // exp(-0.2) == decay_syn

  float ipre = (tid < 128) ? Iext[(size_t)b * NH + SLICE * p + jj] : 0.0f;

  for (int t = 0; t < T_STEPS; ++t) {
    const int par = t & 1;
    bool spike = false;
    if (tid < 128) {
      const float I = ipre + psc;
      a1 *= D1;
      a2 *= D2;
      v = v + ((-60.0f - v) / 20.0f + (I + a1 + a2) / 2.0f);
      const bool inref = refr > 0.0f;
      if (inref) v = -60.0f;
      spike = (!inref) && (v >= -45.0f);
      if (spike) {
        v = -60.0f; a1 += 1.0f; a2 += -2.0f; refr = 2.0f; scount++;
      } else {
        refr = fmaxf(refr - 1.0f, 0.0f);
      }
    }
    // ballot bit (4*(b&15)+jj) within each wave: exactly nibble-packed layout
    unsigned long long bal = __ballot(spike ? 1 : 0);
    if (widx >= 0) {
      unsigned w32 = (widx & 1) ? (unsigned)(bal >> 32) : (unsigned)bal;
      st64_agent(&sbuf[((size_t)par * NBLK + p) * 4 + widx],
                 (u64)w32 | ((u64)(unsigned)(t + 1) << 32));
    }
    // prefetch next step's external current while polling
    const int tn2 = (t + 1 < T_STEPS) ? t + 1 : t;
    float inext = (tid < 128) ? Iext[(size_t)(tn2 * B_SZ + b) * NH + SLICE * p + jj] : 0.0f;

    // poll my producer (thread tid <-> producer tid): 4 u64s in one 64B line
    const u64 want = (u64)(unsigned)(t + 1);
    const u64* src = &sbuf[((size_t)par * NBLK + tid) * 4];
    u64 q0, q1, q2, q3;
    for (;;) {
      q0 = ld64_agent(src + 0); q1 = ld64_agent(src + 1);
      q2 = ld64_agent(src + 2); q3 = ld64_agent(src + 3);
      if (((q0 >> 32) == want) & ((q1 >> 32) == want) &
          ((q2 >> 32) == want) & ((q3 >> 32) == want)) break;
      __builtin_amdgcn_s_sleep(1);
    }
    raw[0][tid] = (unsigned)q0;
    raw[1][tid] = (unsigned)q1;
    raw[2][tid] = (unsigned)q2;
    raw[3][tid] = (unsigned)q3;
    __syncthreads();

    // build bm[w][cb] for 4 words: 8 consecutive producer words each (2x b128 read)
#pragma unroll
    for (int wi = 0; wi < 4; ++wi) {
      const int w = cw0 + 8 * wi;
      const unsigned* rr = &raw[crow][8 * w];
      unsigned u = 0;
#pragma unroll
      for (int k = 0; k < 8; ++k) u |= ((rr[k] >> csh) & 0xFu) << (4 * k);
      bm[w][cb] = u;
    }
    __syncthreads();

    // sparse gather: rec[b,j] = sum over spiking presyn i of W_rec[j,i]
    float s = 0.0f;
    for (int w = half * 16; w < half * 16 + 16; ++w) {
      unsigned m = bm[w][b];
      while (m) {
        const int bit = __builtin_ctz(m);
        m &= m - 1;
        s += wbase[(size_t)(w * 32 + bit) * SLICE];
      }
    }
    psum[tid] = s;
    __syncthreads();
    if (tid < 128) {
      const float rec = s + psum[tid + 128];
      h = D2 * h + rec;
      psc = D2 * psc + h;   // psc uses updated h (matches reference)
    }
    ipre = inext;
  }

  if (tid < 128) rate[(size_t)b * NH + SLICE * p + jj] = (float)scount / 1000.0f;
}

// ---------------- kernel 4: out = rate @ W_out^T ----------------
__global__ __launch_bounds__(256) void out_gemv(const float* __restrict__ rate,
                                                const float* __restrict__ Wout,
                                                float* __restrict__ out) {
  __shared__ float rs[NH];
  const int b = blockIdx.x, tid = threadIdx.x;
  for (int i = tid; i < NH; i += 256) rs[i] = rate[(size_t)b * NH + i];
  __syncthreads();
  const float* wr = Wout + (size_t)tid * NH;
  float s = 0.0f;
  for (int hh = 0; hh < NH; hh += 4) {
    float4 w4 = *(const float4*)&wr[hh];
    s += rs[hh] * w4.x + rs[hh + 1] * w4.y + rs[hh + 2] * w4.z + rs[hh + 3] * w4.w;
  }
  out[(size_t)b * NO + tid] = s;
}

// ---------------- launch ----------------
extern "C" void kernel_launch(void* const* d_in, const int* in_sizes, int n_in,
                              void* d_out, int out_size, void* d_ws, size_t ws_size,
                              hipStream_t stream) {
  const float* x    = (const float*)d_in[0];
  const float* Win  = (const float*)d_in[1];
  const float* Wrec = (const float*)d_in[2];
  const float* Wout = (const float*)d_in[3];
  float* out = (float*)d_out;

  char* ws = (char*)d_ws;
  float* Iext = (float*)(ws + OFF_IEXT);
  float* WP   = (float*)(ws + OFF_WP);
  float* rate = (float*)(ws + OFF_RATE);
  u64*   sbuf = (u64*)(ws + OFF_SYNC);
  // No memset needed: 0xAA poison (tag 0xAAAAAAAA) never equals t+1 <= 1000,
  // and every block publishes before polling -> no deadlock, no false match.

  prep_wp<<<dim3(NBLK), dim3(256), 0, stream>>>(Wrec, WP);
  gemm_in<<<dim3((T_STEPS * B_SZ) / GBM, NH / GBN), dim3(256), 0, stream>>>(x, Win, Iext);
  scan_rsnn<<<dim3(NBLK), dim3(256), 0, stream>>>(Iext, WP, rate, sbuf);
  out_gemv<<<dim3(B_SZ), dim3(256), 0, stream>>>(rate, Wout, out);
}